// Round 1
// baseline (243.334 us; speedup 1.0000x reference)
//
#include <hip/hip_runtime.h>
#include <math.h>

#define C_CH 128
#define HW 128
#define KK 5
#define PAD 2
#define TILE_ROWS 32
#define LDS_ROWS (TILE_ROWS + 2*PAD)          // 36
#define NW (KK*KK*C_CH + C_CH)                // 3328 weights per sample
#define N_TILES (HW / TILE_ROWS)              // 4
#define CHUNKS ((LDS_ROWS * HW * 4) / 1024)   // 18 chunks of 1024 B

__global__ __launch_bounds__(256, 8) void hyperconv_dw_silu(
    const float* __restrict__ inp, const float* __restrict__ wts,
    float* __restrict__ out)
{
    // Linear (unpadded) LDS tile: rows contiguous -> global_load_lds-compatible.
    __shared__ float s[LDS_ROWS][HW];         // 18432 B -> 8 blocks/CU

    const int tid  = threadIdx.x;
    const int tile = blockIdx.x;   // row strip 0..3
    const int c    = blockIdx.y;   // channel
    const int b    = blockIdx.z;   // batch

    // Block-uniform weights -> scalar loads / SGPRs
    const float* wt = wts + (size_t)b * NW;
    float wk[25];
#pragma unroll
    for (int j = 0; j < 25; ++j) wk[j] = wt[c * 25 + j];
    const float bias = wt[KK * KK * C_CH + c];

    const int row0 = tile * TILE_ROWS;
    const float* plane = inp + ((size_t)(b * C_CH + c)) * (HW * HW);
    const float* src0  = plane + (row0 - PAD) * HW;  // LDS row 0 == global row row0-2

    const int wave = tid >> 6;
    const int lane = tid & 63;

    // ---- async global->LDS staging: 18 chunks x 1024 B (64 lanes x 16 B) ----
    // chunk ch covers LDS rows {2ch, 2ch+1}. Chunk 0 of tile 0 and chunk 17 of
    // tile 3 would read outside the image -> skip and zero-fill instead.
    for (int ch = wave; ch < CHUNKS; ch += 4) {
        const bool oob = (tile == 0 && ch == 0) ||
                         (tile == N_TILES - 1 && ch == CHUNKS - 1);
        if (!oob) {
            __builtin_amdgcn_global_load_lds(
                (const __attribute__((address_space(1))) void*)(src0 + ch * 256 + lane * 4),
                (__attribute__((address_space(3))) void*)((char*)&s[0][0] + ch * 1024),
                16, 0, 0);
        }
    }
    if (tile == 0 && tid < 64)
        *(float4*)((char*)&s[0][0] + tid * 16) = make_float4(0.f, 0.f, 0.f, 0.f);
    if (tile == N_TILES - 1 && tid < 64)
        *(float4*)((char*)&s[0][0] + (CHUNKS - 1) * 1024 + tid * 16) =
            make_float4(0.f, 0.f, 0.f, 0.f);
    __syncthreads();   // compiler drains vmcnt(0) (incl. LDS-DMA) before s_barrier

    // ---- compute: each thread = 4 output rows x 4 output cols ----
    const int colg = tid & 31;        // cols 4*colg .. 4*colg+3
    const int rowg = tid >> 5;        // local rows 4*rowg .. 4*rowg+3
    const int ro   = rowg * 4;
    const int xb   = colg * 4;

    // window cols xb-2..xb+5 via three aligned b128 reads (contiguous pattern,
    // conflict-free); edge lanes clamp the address and cndmask-zero the taps.
    const int lcb = (colg == 0)  ? 0   : (xb - 4);
    const int rcb = (colg == 31) ? 120 : (xb + 4);

    float acc[4][4];
#pragma unroll
    for (int i = 0; i < 4; ++i)
#pragma unroll
        for (int j = 0; j < 4; ++j) acc[i][j] = bias;

#pragma unroll
    for (int r = 0; r < 8; ++r) {
        const float* srow = &s[ro + r][0];
        const float4 xl = *(const float4*)(srow + lcb);
        const float4 xm = *(const float4*)(srow + xb);
        const float4 xr = *(const float4*)(srow + rcb);
        float x[8];
        x[0] = (colg == 0)  ? 0.f : xl.z;   // col xb-2
        x[1] = (colg == 0)  ? 0.f : xl.w;   // col xb-1
        x[2] = xm.x; x[3] = xm.y; x[4] = xm.z; x[5] = xm.w;
        x[6] = (colg == 31) ? 0.f : xr.x;   // col xb+4
        x[7] = (colg == 31) ? 0.f : xr.y;   // col xb+5

#pragma unroll
        for (int orow = 0; orow < 4; ++orow) {
            const int kh = r - orow;              // tap row
            if (kh < 0 || kh > 4) continue;       // resolved at compile time
#pragma unroll
            for (int oc = 0; oc < 4; ++oc)
#pragma unroll
                for (int kw = 0; kw < 5; ++kw)
                    acc[orow][oc] = fmaf(wk[kh * 5 + kw], x[oc + kw], acc[orow][oc]);
        }
    }

    // epilogue: fast SiLU (v_exp + v_rcp) + coalesced float4 stores
    float* oplane = out + ((size_t)(b * C_CH + c)) * (HW * HW);
#pragma unroll
    for (int orow = 0; orow < 4; ++orow) {
        float v0 = acc[orow][0], v1 = acc[orow][1];
        float v2 = acc[orow][2], v3 = acc[orow][3];
        float4 o;
        o.x = v0 * __builtin_amdgcn_rcpf(1.0f + __expf(-v0));
        o.y = v1 * __builtin_amdgcn_rcpf(1.0f + __expf(-v1));
        o.z = v2 * __builtin_amdgcn_rcpf(1.0f + __expf(-v2));
        o.w = v3 * __builtin_amdgcn_rcpf(1.0f + __expf(-v3));
        *(float4*)(oplane + (size_t)(row0 + ro + orow) * HW + xb) = o;
    }
}

extern "C" void kernel_launch(void* const* d_in, const int* in_sizes, int n_in,
                              void* d_out, int out_size, void* d_ws, size_t ws_size,
                              hipStream_t stream) {
    const float* inp = (const float*)d_in[0];
    const float* wts = (const float*)d_in[1];
    float* out = (float*)d_out;

    const int batch = in_sizes[1] / NW;   // 16
    dim3 grid(N_TILES, C_CH, batch);
    hyperconv_dw_silu<<<grid, 256, 0, stream>>>(inp, wts, out);
}

// Round 3
// 233.352 us; speedup vs baseline: 1.0428x; 1.0428x over previous
//
#include <hip/hip_runtime.h>
#include <math.h>

#define C_CH 128
#define HW 128
#define KK 5
#define NW (KK*KK*C_CH + C_CH)   // 3328 weights per sample
#define TROWS 32                 // output rows per tile
#define LROWS 36                 // staged rows per tile (with +/-2 halo)
#define WSPAN 4608               // per-wave contiguous span (18432/4)

typedef const __attribute__((address_space(1))) void* gp_t;
typedef __attribute__((address_space(3))) void* lp_t;

__device__ __forceinline__ void ld16(const char* g, char* l, int lane) {
    __builtin_amdgcn_global_load_lds((gp_t)(g + lane * 16), (lp_t)l, 16, 0, 0);
}
__device__ __forceinline__ void ld4(const char* g, char* l, int lane) {
    __builtin_amdgcn_global_load_lds((gp_t)(g + lane * 4), (lp_t)l, 4, 0, 0);
}

// Stage tile t (global rows 32t-2 .. 32t+33) into buf. Each wave owns a
// contiguous 4608 B span as 4x ld16 (1024 B) + 2x ld4 (256 B) = 6 VMEM ops
// (only measured DMA widths: 16 B and 4 B). Boundary chunks are whole ld16s:
// wave0's span STARTS with the top-halo KiB (rows 0,1); wave3's span ENDS
// with the bottom-halo KiB (rows 34,35).
// skipmode: 0 none, 1 = skip wave0 first ld16 (t==0), 2 = skip wave3 last (t==3)
__device__ __forceinline__ void stage(const float* plane, int t, float* buf,
                                      int wave, int lane, int skipmode) {
    const char* g = (const char*)plane + (long)(TROWS * t - 2) * (HW * 4) + wave * WSPAN;
    char* l = (char*)buf + wave * WSPAN;
    if (wave < 3) {
        if (!(skipmode == 1 && wave == 0)) ld16(g, l, lane);
        ld16(g + 1024, l + 1024, lane);
        ld16(g + 2048, l + 2048, lane);
        ld16(g + 3072, l + 3072, lane);
        ld4 (g + 4096, l + 4096, lane);
        ld4 (g + 4352, l + 4352, lane);
    } else {
        ld4 (g,        l,        lane);
        ld4 (g + 256,  l + 256,  lane);
        ld16(g + 512,  l + 512,  lane);
        ld16(g + 1536, l + 1536, lane);
        ld16(g + 2560, l + 2560, lane);
        if (skipmode != 2) ld16(g + 3584, l + 3584, lane);  // buf bytes 17408..18431
    }
}

__device__ __forceinline__ void compute_tile(const float (*s)[HW], int t,
                                             int rowg, int colg,
                                             const float* wk, float bias,
                                             float* oplane) {
    const int ro = rowg * 4;
    const int xb = colg * 4;
    const int lcb = (colg == 0)  ? 0   : (xb - 4);
    const int rcb = (colg == 31) ? 120 : (xb + 4);

    float acc[4][4];
#pragma unroll
    for (int i = 0; i < 4; ++i)
#pragma unroll
        for (int j = 0; j < 4; ++j) acc[i][j] = bias;

#pragma unroll
    for (int r = 0; r < 8; ++r) {
        const float* srow = &s[ro + r][0];
        const float4 xl = *(const float4*)(srow + lcb);
        const float4 xm = *(const float4*)(srow + xb);
        const float4 xr = *(const float4*)(srow + rcb);
        float x[8];
        x[0] = (colg == 0)  ? 0.f : xl.z;
        x[1] = (colg == 0)  ? 0.f : xl.w;
        x[2] = xm.x; x[3] = xm.y; x[4] = xm.z; x[5] = xm.w;
        x[6] = (colg == 31) ? 0.f : xr.x;
        x[7] = (colg == 31) ? 0.f : xr.y;

#pragma unroll
        for (int orow = 0; orow < 4; ++orow) {
            const int kh = r - orow;
            if (kh < 0 || kh > 4) continue;   // compile-time
#pragma unroll
            for (int oc = 0; oc < 4; ++oc)
#pragma unroll
                for (int kw = 0; kw < 5; ++kw)
                    acc[orow][oc] = fmaf(wk[kh * 5 + kw], x[oc + kw], acc[orow][oc]);
        }
    }

#pragma unroll
    for (int orow = 0; orow < 4; ++orow) {
        float v0 = acc[orow][0], v1 = acc[orow][1];
        float v2 = acc[orow][2], v3 = acc[orow][3];
        float4 o;
        o.x = v0 * __builtin_amdgcn_rcpf(1.0f + __expf(-v0));
        o.y = v1 * __builtin_amdgcn_rcpf(1.0f + __expf(-v1));
        o.z = v2 * __builtin_amdgcn_rcpf(1.0f + __expf(-v2));
        o.w = v3 * __builtin_amdgcn_rcpf(1.0f + __expf(-v3));
        *(float4*)(oplane + (size_t)(TROWS * t + ro + orow) * HW + xb) = o;
    }
}

// counted waitcnt + raw barrier, fenced on BOTH sides (rule 18 + anti-hoist
// insurance: no ds_read may move above the barrier into the post-wait window)
#define PHASE_SYNC(str) do { \
    asm volatile(str ::: "memory"); \
    __builtin_amdgcn_sched_barrier(0); \
    __builtin_amdgcn_s_barrier(); \
    __builtin_amdgcn_sched_barrier(0); } while (0)

__global__ __launch_bounds__(256, 4) void hyperconv_dw_silu(
    const float* __restrict__ inp, const float* __restrict__ wts,
    float* __restrict__ out)
{
    __shared__ float sA[LROWS][HW];   // 18432 B each, double-buffered
    __shared__ float sB[LROWS][HW];

    const int tid  = threadIdx.x;
    const int wave = tid >> 6;
    const int lane = tid & 63;
    const int c    = blockIdx.x;   // channel (block-uniform -> scalar weights)
    const int b    = blockIdx.y;   // batch

    const float* wt = wts + (size_t)b * NW;
    float wk[25];
#pragma unroll
    for (int j = 0; j < 25; ++j) wk[j] = wt[c * 25 + j];
    const float bias = wt[KK * KK * C_CH + c];

    const float* plane  = inp + ((size_t)(b * C_CH + c)) * (HW * HW);
    float*       oplane = out + ((size_t)(b * C_CH + c)) * (HW * HW);

    const int colg = tid & 31;
    const int rowg = tid >> 5;

    // ---- prologue: stage tiles 0,1; zero the top halo (rows -2,-1) ----
    stage(plane, 0, &sA[0][0], wave, lane, 1);      // wave0: 5 ops, others: 6
    if (tid < 64)
        *(float4*)((char*)&sA[0][0] + tid * 16) = make_float4(0.f, 0.f, 0.f, 0.f);
    stage(plane, 1, &sB[0][0], wave, lane, 0);      // 6 ops/wave

    // ---- t=0 : stage0 done; stage1 (6/wave) stays in flight ----
    PHASE_SYNC("s_waitcnt vmcnt(6) lgkmcnt(0)");
    compute_tile(sA, 0, rowg, colg, wk, bias, oplane);   // +4 stores
    PHASE_SYNC("s_waitcnt lgkmcnt(0)");                  // all waves done reading sA
    stage(plane, 2, &sA[0][0], wave, lane, 0);           // 6 ops/wave

    // ---- t=1 : stage1 done; 4 stores(t0) + 6 loads(stage2) in flight ----
    PHASE_SYNC("s_waitcnt vmcnt(10)");
    compute_tile(sB, 1, rowg, colg, wk, bias, oplane);   // +4 stores
    PHASE_SYNC("s_waitcnt lgkmcnt(0)");                  // all waves done reading sB
    stage(plane, 3, &sB[0][0], wave, lane, 2);           // wave3: 5 ops, others: 6
    if (wave == 3)                                       // zero bottom halo (rows 34,35)
        *(float4*)((char*)&sB[0][0] + 17408 + lane * 16) =
            make_float4(0.f, 0.f, 0.f, 0.f);

    // ---- t=2 : stage2 done; 4 stores(t1) + >=5 loads(stage3) in flight ----
    PHASE_SYNC("s_waitcnt vmcnt(9)");
    compute_tile(sA, 2, rowg, colg, wk, bias, oplane);   // +4 stores

    // ---- t=3 : stage3 done (4 stores of t2 in flight); lgkm covers halo fill ----
    PHASE_SYNC("s_waitcnt vmcnt(4) lgkmcnt(0)");
    compute_tile(sB, 3, rowg, colg, wk, bias, oplane);
}

extern "C" void kernel_launch(void* const* d_in, const int* in_sizes, int n_in,
                              void* d_out, int out_size, void* d_ws, size_t ws_size,
                              hipStream_t stream) {
    const float* inp = (const float*)d_in[0];
    const float* wts = (const float*)d_in[1];
    float* out = (float*)d_out;

    const int batch = in_sizes[1] / NW;   // 16
    dim3 grid(C_CH, batch);               // one block per (channel, batch) plane
    hyperconv_dw_silu<<<grid, 256, 0, stream>>>(inp, wts, out);
}